// Round 1
// baseline (1243.147 us; speedup 1.0000x reference)
//
#include <hip/hip_runtime.h>
#include <math.h>

#define LL 2
#define BB 32
#define SS 2048
#define HH 512
#define DD 1024      // 2*H
#define W4S 2048     // attn_w row stride = 4*H

#define BM 64
#define BN 64
#define BK 16

// ---------------- zero init (scores ws + context out get atomics) -------------
__global__ void k_zero(float* __restrict__ scores, float* __restrict__ ctx) {
    int i = blockIdx.x * 256 + threadIdx.x;   // grid covers BB*SS
    scores[i] = 0.f;
    if (i < BB * DD) ctx[i] = 0.f;
}

// ---------------- base[b,h] = dot(hidden[-1,b,:], w_h[h,:]) + bias[h] --------
__global__ __launch_bounds__(256) void k_base(const float* __restrict__ hidden,
                                              const float* __restrict__ attn_w,
                                              const float* __restrict__ attn_b,
                                              float* __restrict__ base) {
    int wid  = (blockIdx.x * 256 + threadIdx.x) >> 6;   // one wave per (b,h)
    int lane = threadIdx.x & 63;
    int b = wid >> 9;          // / HH
    int h = wid & (HH - 1);
    const float* hrow = hidden + (size_t)(LL - 1) * BB * DD + (size_t)b * DD;
    const float* wrow = attn_w + (size_t)h * W4S;       // w_h = first DD cols
    float s = 0.f;
    for (int i = lane; i < DD; i += 64) s += hrow[i] * wrow[i];
    #pragma unroll
    for (int off = 32; off; off >>= 1) s += __shfl_xor(s, off);
    if (lane == 0) base[b * HH + h] = s + attn_b[h];
}

// ---------------- big GEMM + fused tanh·v reduction --------------------------
// C[m, n] = sum_k enc[m, k] * w_e[n, k];  m = b*SS + s, n = h
// scores[m] += sum_n tanh(C[m,n] + base[b,n]) * v[n]
__global__ __launch_bounds__(256) void k_scores(const float* __restrict__ enc,
                                                const float* __restrict__ attn_w,
                                                const float* __restrict__ base,
                                                const float* __restrict__ vw,
                                                float* __restrict__ scores) {
    __shared__ float As[BK][68];   // k-major, padded to 68 (16B-aligned float4 rows)
    __shared__ float Bs[BK][68];
    const int tid = threadIdx.x;
    const int n0  = blockIdx.x * BN;
    const int m0  = blockIdx.y * BM;
    const int b   = m0 >> 11;                 // SS = 2048; 64 | 2048 so b is tile-uniform
    const int row = tid >> 2;                 // 0..63 (tile row for staging)
    const int kq  = (tid & 3) << 2;           // 0,4,8,12
    const int tx  = tid & 15;                 // column group
    const int ty  = tid >> 4;                 // row group

    const float* Ag = enc    + (size_t)(m0 + row) * DD  + kq;
    const float* Bg = attn_w + (size_t)(n0 + row) * W4S + DD + kq;  // w_e

    float acc[4][4] = {};
    for (int kt = 0; kt < DD; kt += BK) {
        float4 av = *(const float4*)(Ag + kt);
        float4 bv = *(const float4*)(Bg + kt);
        __syncthreads();
        As[kq + 0][row] = av.x; As[kq + 1][row] = av.y;
        As[kq + 2][row] = av.z; As[kq + 3][row] = av.w;
        Bs[kq + 0][row] = bv.x; Bs[kq + 1][row] = bv.y;
        Bs[kq + 2][row] = bv.z; Bs[kq + 3][row] = bv.w;
        __syncthreads();
        #pragma unroll
        for (int kk = 0; kk < BK; kk++) {
            float4 a  = *(const float4*)&As[kk][ty << 2];
            float4 bq = *(const float4*)&Bs[kk][tx << 2];
            float ar[4] = {a.x, a.y, a.z, a.w};
            float br[4] = {bq.x, bq.y, bq.z, bq.w};
            #pragma unroll
            for (int r = 0; r < 4; r++)
                #pragma unroll
                for (int c = 0; c < 4; c++)
                    acc[r][c] += ar[r] * br[c];
        }
    }

    // epilogue: tanh + v-weighted reduction over the 64 columns of this tile
    float part[4];
    #pragma unroll
    for (int r = 0; r < 4; r++) {
        float p = 0.f;
        #pragma unroll
        for (int c = 0; c < 4; c++) {
            int n  = n0 + (tx << 2) + c;
            float t = tanhf(acc[r][c] + base[b * HH + n]);
            p += t * vw[n];
        }
        part[r] = p;
    }
    #pragma unroll
    for (int off = 8; off; off >>= 1) {
        #pragma unroll
        for (int r = 0; r < 4; r++) part[r] += __shfl_xor(part[r], off);
    }
    if (tx == 0) {
        #pragma unroll
        for (int r = 0; r < 4; r++)
            atomicAdd(&scores[m0 + (ty << 2) + r], part[r]);
    }
}

// ---------------- softmax over S per batch -----------------------------------
__global__ __launch_bounds__(256) void k_softmax(const float* __restrict__ scores,
                                                 float* __restrict__ wout) {
    int b = blockIdx.x, tid = threadIdx.x;
    const float* rowp = scores + b * SS;
    float v[8];
    float m = -1e30f;
    #pragma unroll
    for (int i = 0; i < 8; i++) { v[i] = rowp[tid + i * 256]; m = fmaxf(m, v[i]); }
    __shared__ float sm[4], ssum[4];
    #pragma unroll
    for (int off = 32; off; off >>= 1) m = fmaxf(m, __shfl_xor(m, off));
    if ((tid & 63) == 0) sm[tid >> 6] = m;
    __syncthreads();
    m = fmaxf(fmaxf(sm[0], sm[1]), fmaxf(sm[2], sm[3]));
    float s = 0.f;
    #pragma unroll
    for (int i = 0; i < 8; i++) { v[i] = __expf(v[i] - m); s += v[i]; }
    #pragma unroll
    for (int off = 32; off; off >>= 1) s += __shfl_xor(s, off);
    if ((tid & 63) == 0) ssum[tid >> 6] = s;
    __syncthreads();
    s = ssum[0] + ssum[1] + ssum[2] + ssum[3];
    float inv = 1.f / s;
    #pragma unroll
    for (int i = 0; i < 8; i++) wout[b * SS + tid + i * 256] = v[i] * inv;
}

// ---------------- context[b,d] = sum_s w[b,s]*enc[b,s,d] ---------------------
__global__ __launch_bounds__(256) void k_context(const float* __restrict__ enc,
                                                 const float* __restrict__ w,
                                                 float* __restrict__ ctx) {
    int b = blockIdx.x, chunk = blockIdx.y, tid = threadIdx.x;
    __shared__ float wsh[256];
    int s0 = chunk * 256;
    wsh[tid] = w[b * SS + s0 + tid];
    __syncthreads();
    const float4* e4 = (const float4*)(enc + (size_t)b * SS * DD);
    float4 acc = {0.f, 0.f, 0.f, 0.f};
    for (int s = 0; s < 256; s++) {
        float wv  = wsh[s];
        float4 ev = e4[(size_t)(s0 + s) * (DD / 4) + tid];
        acc.x += wv * ev.x; acc.y += wv * ev.y;
        acc.z += wv * ev.z; acc.w += wv * ev.w;
    }
    float* c = ctx + b * DD + tid * 4;
    atomicAdd(c + 0, acc.x); atomicAdd(c + 1, acc.y);
    atomicAdd(c + 2, acc.z); atomicAdd(c + 3, acc.w);
}

extern "C" void kernel_launch(void* const* d_in, const int* in_sizes, int n_in,
                              void* d_out, int out_size, void* d_ws, size_t ws_size,
                              hipStream_t stream) {
    const float* hidden = (const float*)d_in[0];   // (L,B,D)
    const float* enc    = (const float*)d_in[1];   // (B,S,D)
    const float* attn_w = (const float*)d_in[2];   // (H,4H)
    const float* attn_b = (const float*)d_in[3];   // (H,)
    const float* v_w    = (const float*)d_in[4];   // (1,H)

    float* out      = (float*)d_out;
    float* ctx_out  = out;               // (B,1,D) flat = B*D
    float* attn_out = out + BB * DD;     // (B,1,S) flat = B*S

    float* base   = (float*)d_ws;        // B*H floats
    float* scores = base + BB * HH;      // B*S floats

    hipLaunchKernelGGL(k_zero, dim3(BB * SS / 256), dim3(256), 0, stream,
                       scores, ctx_out);
    hipLaunchKernelGGL(k_base, dim3(BB * HH / 4), dim3(256), 0, stream,
                       hidden, attn_w, attn_b, base);
    hipLaunchKernelGGL(k_scores, dim3(HH / BN, BB * SS / BM), dim3(256), 0, stream,
                       enc, attn_w, base, v_w, scores);
    hipLaunchKernelGGL(k_softmax, dim3(BB), dim3(256), 0, stream,
                       scores, attn_out);
    hipLaunchKernelGGL(k_context, dim3(BB, SS / 256), dim3(256), 0, stream,
                       enc, attn_out, ctx_out);
}

// Round 2
// 596.612 us; speedup vs baseline: 2.0837x; 2.0837x over previous
//
#include <hip/hip_runtime.h>
#include <math.h>

#define LL 2
#define BB 32
#define SS 2048
#define HH 512
#define DD 1024      // 2*H
#define W4S 2048     // attn_w row stride = 4*H

// k_scores MFMA tiling
#define BM 64
#define BN 256
#define BK 32
#define LDST 40      // padded LDS row stride in shorts (80 B, multiple of 16 B)

typedef __attribute__((ext_vector_type(8))) short bf16x8;
typedef __attribute__((ext_vector_type(4))) float f32x4;

// round-to-nearest-even fp32 -> bf16, packed pair
__device__ inline unsigned pk2(float a, float b) {
    unsigned ua = __float_as_uint(a), ub = __float_as_uint(b);
    unsigned ra = (ua + 0x7fffu + ((ua >> 16) & 1u)) >> 16;
    unsigned rb = (ub + 0x7fffu + ((ub >> 16) & 1u)) & 0xffff0000u;
    return ra | rb;
}

__device__ inline float fast_tanh(float x) {
    x = fminf(9.f, fmaxf(-9.f, x));
    float e = __expf(2.f * x);
    return 1.f - 2.f * __builtin_amdgcn_rcpf(e + 1.f);
}

// ---------------- zero init (scores ws + context out get atomics) -------------
__global__ void k_zero(float* __restrict__ scores, float* __restrict__ ctx) {
    int i = blockIdx.x * 256 + threadIdx.x;   // grid covers BB*SS
    scores[i] = 0.f;
    if (i < BB * DD) ctx[i] = 0.f;
}

// ---------------- base[b,h] = dot(hidden[-1,b,:], w_h[h,:]) + bias[h] --------
__global__ __launch_bounds__(256) void k_base(const float* __restrict__ hidden,
                                              const float* __restrict__ attn_w,
                                              const float* __restrict__ attn_b,
                                              float* __restrict__ base) {
    int wid  = (blockIdx.x * 256 + threadIdx.x) >> 6;   // one wave per (b,h)
    int lane = threadIdx.x & 63;
    int b = wid >> 9;          // / HH
    int h = wid & (HH - 1);
    const float* hrow = hidden + (size_t)(LL - 1) * BB * DD + (size_t)b * DD;
    const float* wrow = attn_w + (size_t)h * W4S;       // w_h = first DD cols
    float s = 0.f;
    for (int i = lane; i < DD; i += 64) s += hrow[i] * wrow[i];
    #pragma unroll
    for (int off = 32; off; off >>= 1) s += __shfl_xor(s, off);
    if (lane == 0) base[b * HH + h] = s + attn_b[h];
}

// ---------------- big GEMM (bf16 MFMA) + fused tanh·v reduction --------------
// C[m,n] = sum_k enc[m,k] * w_e[n,k];  m = b*SS + s, n = h  (NT layout)
// scores[m] += sum_n tanh(C[m,n] + base[b,n]) * v[n]
__global__ __launch_bounds__(256) void k_scores(const float* __restrict__ enc,
                                                const float* __restrict__ attn_w,
                                                const float* __restrict__ base,
                                                const float* __restrict__ vw,
                                                float* __restrict__ scores) {
    __shared__ short As[BM * LDST];   // 64 x 32 bf16, padded rows
    __shared__ short Bs[BN * LDST];   // 256 x 32 bf16, padded rows

    const int tid  = threadIdx.x;
    const int n0   = blockIdx.x * BN;          // 0 or 256
    const int m0   = blockIdx.y * BM;
    const int b    = m0 >> 11;                 // 64 | 2048 -> uniform per block
    const int row8 = tid >> 3;                 // 0..31 (staging row)
    const int col4 = tid & 7;                  // float4 column within BK

    const int wid  = tid >> 6;                 // 0..3
    const int lane = tid & 63;
    const int lm   = lane & 15;
    const int kq   = lane >> 4;                // 0..3
    const int wn   = wid * 64;                 // wave's 64-col slice of BN

    const float* Ag = enc    + (size_t)(m0 + row8) * DD  + col4 * 4;
    const float* Bg = attn_w + (size_t)(n0 + row8) * W4S + DD + col4 * 4; // w_e

    // LDS write/read offsets (in shorts)
    const int wA0 = row8 * LDST + col4 * 4;
    const int wA1 = (row8 + 32) * LDST + col4 * 4;
    const int wB0 = row8 * LDST + col4 * 4;

    f32x4 acc[4][4];
    #pragma unroll
    for (int i = 0; i < 4; i++)
        #pragma unroll
        for (int j = 0; j < 4; j++) acc[i][j] = (f32x4){0.f, 0.f, 0.f, 0.f};

    for (int kt = 0; kt < DD; kt += BK) {
        float4 a0 = *(const float4*)(Ag + kt);
        float4 a1 = *(const float4*)(Ag + (size_t)32 * DD + kt);
        float4 bb[8];
        #pragma unroll
        for (int p = 0; p < 8; p++)
            bb[p] = *(const float4*)(Bg + (size_t)p * 32 * W4S + kt);

        __syncthreads();   // protect LDS from previous iteration's readers
        *(uint2*)&As[wA0] = make_uint2(pk2(a0.x, a0.y), pk2(a0.z, a0.w));
        *(uint2*)&As[wA1] = make_uint2(pk2(a1.x, a1.y), pk2(a1.z, a1.w));
        #pragma unroll
        for (int p = 0; p < 8; p++)
            *(uint2*)&Bs[wB0 + p * 32 * LDST] =
                make_uint2(pk2(bb[p].x, bb[p].y), pk2(bb[p].z, bb[p].w));
        __syncthreads();

        bf16x8 af[4];
        #pragma unroll
        for (int mi = 0; mi < 4; mi++)
            af[mi] = *(bf16x8*)&As[(mi * 16 + lm) * LDST + kq * 8];
        #pragma unroll
        for (int ni = 0; ni < 4; ni++) {
            bf16x8 bf = *(bf16x8*)&Bs[(wn + ni * 16 + lm) * LDST + kq * 8];
            #pragma unroll
            for (int mi = 0; mi < 4; mi++)
                acc[mi][ni] = __builtin_amdgcn_mfma_f32_16x16x32_bf16(
                    af[mi], bf, acc[mi][ni], 0, 0, 0);
        }
    }

    // epilogue: p[mi][r] = sum over this wave's 64 cols of tanh(C+base)*v
    const float* basep = base + b * HH + n0 + wn;
    const float* vp    = vw + n0 + wn;
    float p[4][4] = {};
    #pragma unroll
    for (int ni = 0; ni < 4; ni++) {
        int nl = ni * 16 + lm;
        float bs = basep[nl];
        float vv = vp[nl];
        #pragma unroll
        for (int mi = 0; mi < 4; mi++)
            #pragma unroll
            for (int r = 0; r < 4; r++)
                p[mi][r] += vv * fast_tanh(acc[mi][ni][r] + bs);
    }
    #pragma unroll
    for (int off = 8; off; off >>= 1)
        #pragma unroll
        for (int mi = 0; mi < 4; mi++)
            #pragma unroll
            for (int r = 0; r < 4; r++)
                p[mi][r] += __shfl_xor(p[mi][r], off);
    if (lm == 0) {
        #pragma unroll
        for (int mi = 0; mi < 4; mi++)
            #pragma unroll
            for (int r = 0; r < 4; r++)
                atomicAdd(&scores[m0 + mi * 16 + kq * 4 + r], p[mi][r]);
    }
}

// ---------------- softmax over S per batch -----------------------------------
__global__ __launch_bounds__(256) void k_softmax(const float* __restrict__ scores,
                                                 float* __restrict__ wout) {
    int b = blockIdx.x, tid = threadIdx.x;
    const float* rowp = scores + b * SS;
    float v[8];
    float m = -1e30f;
    #pragma unroll
    for (int i = 0; i < 8; i++) { v[i] = rowp[tid + i * 256]; m = fmaxf(m, v[i]); }
    __shared__ float sm[4], ssum[4];
    #pragma unroll
    for (int off = 32; off; off >>= 1) m = fmaxf(m, __shfl_xor(m, off));
    if ((tid & 63) == 0) sm[tid >> 6] = m;
    __syncthreads();
    m = fmaxf(fmaxf(sm[0], sm[1]), fmaxf(sm[2], sm[3]));
    float s = 0.f;
    #pragma unroll
    for (int i = 0; i < 8; i++) { v[i] = __expf(v[i] - m); s += v[i]; }
    #pragma unroll
    for (int off = 32; off; off >>= 1) s += __shfl_xor(s, off);
    if ((tid & 63) == 0) ssum[tid >> 6] = s;
    __syncthreads();
    s = ssum[0] + ssum[1] + ssum[2] + ssum[3];
    float inv = 1.f / s;
    #pragma unroll
    for (int i = 0; i < 8; i++) wout[b * SS + tid + i * 256] = v[i] * inv;
}

// ---------------- context[b,d] = sum_s w[b,s]*enc[b,s,d] ---------------------
#define CCH 128
__global__ __launch_bounds__(256) void k_context(const float* __restrict__ enc,
                                                 const float* __restrict__ w,
                                                 float* __restrict__ ctx) {
    int b = blockIdx.x, chunk = blockIdx.y, tid = threadIdx.x;
    __shared__ float wsh[CCH];
    int s0 = chunk * CCH;
    if (tid < CCH) wsh[tid] = w[b * SS + s0 + tid];
    __syncthreads();
    const float4* e4 = (const float4*)(enc + (size_t)b * SS * DD);
    float4 acc = {0.f, 0.f, 0.f, 0.f};
    #pragma unroll 4
    for (int s = 0; s < CCH; s++) {
        float wv  = wsh[s];
        float4 ev = e4[(size_t)(s0 + s) * (DD / 4) + tid];
        acc.x += wv * ev.x; acc.y += wv * ev.y;
        acc.z += wv * ev.z; acc.w += wv * ev.w;
    }
    float* c = ctx + b * DD + tid * 4;
    atomicAdd(c + 0, acc.x); atomicAdd(c + 1, acc.y);
    atomicAdd(c + 2, acc.z); atomicAdd(c + 3, acc.w);
}

extern "C" void kernel_launch(void* const* d_in, const int* in_sizes, int n_in,
                              void* d_out, int out_size, void* d_ws, size_t ws_size,
                              hipStream_t stream) {
    const float* hidden = (const float*)d_in[0];   // (L,B,D)
    const float* enc    = (const float*)d_in[1];   // (B,S,D)
    const float* attn_w = (const float*)d_in[2];   // (H,4H)
    const float* attn_b = (const float*)d_in[3];   // (H,)
    const float* v_w    = (const float*)d_in[4];   // (1,H)

    float* out      = (float*)d_out;
    float* ctx_out  = out;               // (B,1,D) flat = B*D
    float* attn_out = out + BB * DD;     // (B,1,S) flat = B*S

    float* base   = (float*)d_ws;        // B*H floats
    float* scores = base + BB * HH;      // B*S floats

    hipLaunchKernelGGL(k_zero, dim3(BB * SS / 256), dim3(256), 0, stream,
                       scores, ctx_out);
    hipLaunchKernelGGL(k_base, dim3(BB * HH / 4), dim3(256), 0, stream,
                       hidden, attn_w, attn_b, base);
    hipLaunchKernelGGL(k_scores, dim3(HH / BN, BB * SS / BM), dim3(256), 0, stream,
                       enc, attn_w, base, v_w, scores);
    hipLaunchKernelGGL(k_softmax, dim3(BB), dim3(256), 0, stream,
                       scores, attn_out);
    hipLaunchKernelGGL(k_context, dim3(BB, SS / CCH), dim3(256), 0, stream,
                       enc, attn_out, ctx_out);
}